// Round 16
// baseline (523.602 us; speedup 1.0000x reference)
//
#include <hip/hip_runtime.h>

#define NN 50000            // nodes
#define NE 800000           // edges (without self loops)
#define NTP (NE + 8 * NN)   // padded-CSR capacity: sum pdeg <= NE+NN + 7*NN

// ---------------- graph preprocessing ----------------

__global__ void zero_deg_kernel(int* deg) {
  int v = blockIdx.x * 256 + threadIdx.x;
  if (v < NN) deg[v] = 0;
}

__global__ void count_deg_kernel(const int* __restrict__ edst, int* __restrict__ deg) {
  int i = blockIdx.x * 256 + threadIdx.x;
  if (i < NE) atomicAdd(&deg[edst[i]], 1);
}

__global__ void dinv_kernel(const int* __restrict__ deg, float* __restrict__ dinv) {
  int v = blockIdx.x * 256 + threadIdx.x;
  if (v < NN) dinv[v] = rsqrtf((float)(deg[v] + 1));   // +1 self loop
}

__device__ __forceinline__ int pdeg_of(int deg) {      // (deg+1) rounded up to x8
  return ((deg + 8) >> 3) << 3;
}

// inclusive scan of padded counts in chunks of 1024
__global__ __launch_bounds__(1024) void scan1_kernel(const int* __restrict__ deg,
                                                     int* __restrict__ incl,
                                                     int* __restrict__ bsum) {
  __shared__ int sd[1024];
  int gid = blockIdx.x * 1024 + threadIdx.x;
  int v = (gid < NN) ? pdeg_of(deg[gid]) : 0;
  sd[threadIdx.x] = v;
  __syncthreads();
  for (int off = 1; off < 1024; off <<= 1) {
    int t = (threadIdx.x >= off) ? sd[threadIdx.x - off] : 0;
    __syncthreads();
    sd[threadIdx.x] += t;
    __syncthreads();
  }
  if (gid < NN) incl[gid] = sd[threadIdx.x];
  if (threadIdx.x == 1023) bsum[blockIdx.x] = sd[1023];
}

__global__ void scan2_kernel(int* bsum, int nb) {
  if (threadIdx.x == 0 && blockIdx.x == 0) {
    int run = 0;
    for (int i = 0; i < nb; ++i) { int t = bsum[i]; bsum[i] = run; run += t; }
  }
}

__global__ void scan3_kernel(const int* __restrict__ deg, const int* __restrict__ incl,
                             const int* __restrict__ bsum, int* __restrict__ offs,
                             int* __restrict__ cursor) {
  int v = blockIdx.x * 256 + threadIdx.x;
  if (v >= NN) return;
  int pd = pdeg_of(deg[v]);
  int o = bsum[v >> 10] + incl[v] - pd;
  offs[v] = o;
  cursor[v] = o;
  if (v == NN - 1) offs[NN] = o + pd;
}

// zero padded edge array (int2 zeros -> weight 0 padding)
__global__ void zero_edges_kernel(int2* edges) {
  int i = blockIdx.x * 256 + threadIdx.x;
  if (i < NTP) edges[i] = make_int2(0, 0);
}

// scatter packed edge: .x = src, .y = float bits of weight
// grid-stride x4: 4 independent atomic->store chains in flight per thread.
#define FILL_STRIDE (832 * 256)
__global__ void fill_kernel(const int* __restrict__ esrc, const int* __restrict__ edst,
                            const float* __restrict__ dinv, int* __restrict__ cursor,
                            int2* __restrict__ edges) {
  int i = blockIdx.x * 256 + threadIdx.x;
  for (; i < NE + NN; i += FILL_STRIDE) {
    int s, d;
    if (i < NE) { s = esrc[i]; d = edst[i]; }
    else        { s = d = i - NE; }           // self loop
    int p = atomicAdd(&cursor[d], 1);
    int2 e;
    e.x = s;
    e.y = __float_as_int(dinv[s] * dinv[d]);
    edges[p] = e;
  }
}

// rowsum[v] = sum of weights (padding contributes 0)
__global__ void rowsum_kernel(const int* __restrict__ offs, const int2* __restrict__ edges,
                              float* __restrict__ rowsum) {
  int v = blockIdx.x * 256 + threadIdx.x;
  if (v >= NN) return;
  float s = 0.f;
  int e1 = offs[v + 1];
  for (int e = offs[v]; e < e1; ++e) s += __int_as_float(edges[e].y);
  rowsum[v] = s;
}

// ---------------- tiny fused-weight prep: W13 = W1 @ W3, b13 = b1 @ W3 ------

__global__ void w13_kernel(const float* __restrict__ W1, const float* __restrict__ W3,
                           float* __restrict__ W13) {
  int idx = blockIdx.x * 256 + threadIdx.x;   // 256*64 outputs
  if (idx >= 256 * 64) return;
  int r = idx >> 6, c = idx & 63;
  float acc = 0.f;
  for (int k = 0; k < 128; ++k) acc += W1[r * 128 + k] * W3[k * 64 + c];
  W13[idx] = acc;
}

__global__ void b13_kernel(const float* __restrict__ b1, const float* __restrict__ W3,
                           float* __restrict__ b13) {
  int c = threadIdx.x;   // 64 threads
  if (c >= 64) return;
  float acc = 0.f;
  for (int k = 0; k < 128; ++k) acc += b1[k] * W3[k * 64 + c];
  b13[c] = acc;
}

// ---------------- dense GEMM: out[M,64] = A[M,K] @ W[K,64] + bias -----------
// 512 threads (8 waves), tile 64x64, K-chunk 32, async double-buffer via
// global_load_lds width=16 (m97 pattern): prefetch chunk t+1 issued BEFORE
// computing chunk t, zero staging VGPRs, one barrier/chunk (drains vmcnt).
// LDS unpadded (DMA needs wave-uniform base + lane*16 contiguity): 32KB,
// thread-cap 4 blocks/CU. xs reads take a 4-way bank conflict (acceptable:
// LDS is not the critical path; R11/R15 lesson: protect VGPR count instead).

typedef const unsigned int __attribute__((address_space(1)))* gp32;
typedef unsigned int __attribute__((address_space(3)))* lp32;

template <int K>
__global__ __launch_bounds__(512) void gemm64_kernel(const float* __restrict__ A,
                                                     const float* __restrict__ W,
                                                     const float* __restrict__ bias,
                                                     float* __restrict__ out, int M) {
  __shared__ __align__(16) float xs[2][64][32];
  __shared__ __align__(16) float ws[2][32][64];

  int tid = threadIdx.x;
  int lane = tid & 63;
  int wv = tid >> 6;              // wave 0..7
  int tc = tid & 15;              // col group (4 cols)
  int tr = tid >> 4;              // row group 0..31 (2 rows)
  int row0 = blockIdx.x * 64;

  // staging: wave wv DMAs xs rows [8wv,8wv+8) and ws k-rows [4wv,4wv+4).
  // lane l writes LDS base + l*16; global source matches that layout.
  int xrow = row0 + wv * 8 + (lane >> 3);
  if (xrow > M - 1) xrow = M - 1;                  // clamp (tail block)
  const float* gx = &A[(size_t)xrow * K + (lane & 7) * 4];
  const float* gw = &W[(size_t)(wv * 4 + (lane >> 4)) * 64 + (lane & 15) * 4];

  auto stage = [&](int t) {
    int b = t & 1;
    int kc = t * 32;
    __builtin_amdgcn_global_load_lds((gp32)(const void*)(gx + kc),
                                     (lp32)(void*)&xs[b][wv * 8][0], 16, 0, 0);
    __builtin_amdgcn_global_load_lds((gp32)(const void*)(gw + (size_t)kc * 64),
                                     (lp32)(void*)&ws[b][wv * 4][0], 16, 0, 0);
  };

  float acc[2][4] = {};
  constexpr int NCH = K / 32;

  stage(0);
  __syncthreads();                 // drains vmcnt -> buf0 ready

  for (int t = 0; t < NCH; ++t) {
    int cur = t & 1;
    if (t + 1 < NCH) stage(t + 1);  // async prefetch, no registers held
#pragma unroll
    for (int kk = 0; kk < 32; kk += 4) {
      float4 xv[2], wvv[4];
#pragma unroll
      for (int r = 0; r < 2; ++r)
        xv[r] = *reinterpret_cast<const float4*>(&xs[cur][tr * 2 + r][kk]);
#pragma unroll
      for (int q = 0; q < 4; ++q)
        wvv[q] = *reinterpret_cast<const float4*>(&ws[cur][kk + q][tc * 4]);
#pragma unroll
      for (int r = 0; r < 2; ++r) {
        acc[r][0] += xv[r].x * wvv[0].x + xv[r].y * wvv[1].x + xv[r].z * wvv[2].x + xv[r].w * wvv[3].x;
        acc[r][1] += xv[r].x * wvv[0].y + xv[r].y * wvv[1].y + xv[r].z * wvv[2].y + xv[r].w * wvv[3].y;
        acc[r][2] += xv[r].x * wvv[0].z + xv[r].y * wvv[1].z + xv[r].z * wvv[2].z + xv[r].w * wvv[3].z;
        acc[r][3] += xv[r].x * wvv[0].w + xv[r].y * wvv[1].w + xv[r].z * wvv[2].w + xv[r].w * wvv[3].w;
      }
    }
    __syncthreads();               // waits vmcnt(0): prefetch landed, reads done
  }

  float4 bv = *reinterpret_cast<const float4*>(&bias[tc * 4]);
#pragma unroll
  for (int r = 0; r < 2; ++r) {
    int row = row0 + tr * 2 + r;
    if (row < M) {
      float4 o;
      o.x = acc[r][0] + bv.x;
      o.y = acc[r][1] + bv.y;
      o.z = acc[r][2] + bv.z;
      o.w = acc[r][3] + bv.w;
      *reinterpret_cast<float4*>(&out[(size_t)row * 64 + tc * 4]) = o;
    }
  }
}

// ---------------- propagation (F=64): out[d] = sum_e w_e * h[src_e] --------
// MODE 0: plain   MODE 1: APPNP (0.9*acc + 0.1*h0)   MODE 2: final (+rowsum*b3)
// 16 threads/node; padded 8-aligned int2 CSR segments -> no tails, int4
// metadata loads. At the random-gather transaction ceiling (R13/R14 evidence).

template <int MODE>
__global__ __launch_bounds__(256) void prop64_kernel(const float* __restrict__ hin,
                                                     const float* __restrict__ h0,
                                                     float* __restrict__ out,
                                                     const int* __restrict__ offs,
                                                     const int2* __restrict__ edges,
                                                     const float* __restrict__ rowsum,
                                                     const float* __restrict__ b3) {
  int node = blockIdx.x * 16 + (threadIdx.x >> 4);
  if (node >= NN) return;
  int f = (threadIdx.x & 15) * 4;
  const float* __restrict__ hb = hin + f;

  int e = offs[node];
  int e1 = offs[node + 1];
  float ax = 0.f, ay = 0.f, az = 0.f, aw = 0.f;

  for (; e < e1; e += 8) {
    int4 m01 = *reinterpret_cast<const int4*>(edges + e);
    int4 m23 = *reinterpret_cast<const int4*>(edges + e + 2);
    int4 m45 = *reinterpret_cast<const int4*>(edges + e + 4);
    int4 m67 = *reinterpret_cast<const int4*>(edges + e + 6);
    float4 v0 = *reinterpret_cast<const float4*>(hb + (size_t)m01.x * 64);
    float4 v1 = *reinterpret_cast<const float4*>(hb + (size_t)m01.z * 64);
    float4 v2 = *reinterpret_cast<const float4*>(hb + (size_t)m23.x * 64);
    float4 v3 = *reinterpret_cast<const float4*>(hb + (size_t)m23.z * 64);
    float4 v4 = *reinterpret_cast<const float4*>(hb + (size_t)m45.x * 64);
    float4 v5 = *reinterpret_cast<const float4*>(hb + (size_t)m45.z * 64);
    float4 v6 = *reinterpret_cast<const float4*>(hb + (size_t)m67.x * 64);
    float4 v7 = *reinterpret_cast<const float4*>(hb + (size_t)m67.z * 64);
    float w0 = __int_as_float(m01.y), w1 = __int_as_float(m01.w);
    float w2 = __int_as_float(m23.y), w3 = __int_as_float(m23.w);
    float w4 = __int_as_float(m45.y), w5 = __int_as_float(m45.w);
    float w6 = __int_as_float(m67.y), w7 = __int_as_float(m67.w);
    ax += w0 * v0.x + w1 * v1.x + w2 * v2.x + w3 * v3.x
        + w4 * v4.x + w5 * v5.x + w6 * v6.x + w7 * v7.x;
    ay += w0 * v0.y + w1 * v1.y + w2 * v2.y + w3 * v3.y
        + w4 * v4.y + w5 * v5.y + w6 * v6.y + w7 * v7.y;
    az += w0 * v0.z + w1 * v1.z + w2 * v2.z + w3 * v3.z
        + w4 * v4.z + w5 * v5.z + w6 * v6.z + w7 * v7.z;
    aw += w0 * v0.w + w1 * v1.w + w2 * v2.w + w3 * v3.w
        + w4 * v4.w + w5 * v5.w + w6 * v6.w + w7 * v7.w;
  }

  if (MODE == 1) {
    float4 z = *reinterpret_cast<const float4*>(&h0[(size_t)node * 64 + f]);
    ax = 0.9f * ax + 0.1f * z.x;
    ay = 0.9f * ay + 0.1f * z.y;
    az = 0.9f * az + 0.1f * z.z;
    aw = 0.9f * aw + 0.1f * z.w;
  }
  if (MODE == 2) {
    float rs = rowsum[node];
    float4 bz = *reinterpret_cast<const float4*>(&b3[f]);
    ax += rs * bz.x; ay += rs * bz.y; az += rs * bz.z; aw += rs * bz.w;
  }
  float4 o = make_float4(ax, ay, az, aw);
  *reinterpret_cast<float4*>(&out[(size_t)node * 64 + f]) = o;
}

// ---------------- launch ----------------

extern "C" void kernel_launch(void* const* d_in, const int* in_sizes, int n_in,
                              void* d_out, int out_size, void* d_ws, size_t ws_size,
                              hipStream_t stream) {
  const float* x    = (const float*)d_in[0];   // [50000,256]
  const int*   eidx = (const int*)d_in[1];     // [2,800000]
  const float* W1   = (const float*)d_in[2];   // [256,128]
  const float* b1   = (const float*)d_in[3];   // [128]
  const float* W3   = (const float*)d_in[4];   // [128,64]
  const float* b3   = (const float*)d_in[5];   // [64]
  float* outp = (float*)d_out;                 // [50000,64]

  const int* esrc = eidx;
  const int* edst = eidx + NE;

  // workspace layout (256B aligned)
  char* w = (char*)d_ws;
  size_t off = 0;
  auto take = [&](size_t bytes) {
    void* p = w + off;
    off = (off + bytes + 255) & ~(size_t)255;
    return p;
  };
  int*   deg    = (int*)take(NN * 4);
  float* dinv   = (float*)take(NN * 4);
  int*   incl   = (int*)take(NN * 4);
  int*   offs   = (int*)take((NN + 1) * 4);
  int*   cursor = (int*)take(NN * 4);
  int*   bsum   = (int*)take(64 * 4);
  float* rsum   = (float*)take(NN * 4);
  float* W13    = (float*)take(256 * 64 * 4);
  float* b13    = (float*)take(64 * 4);
  int2*  edges  = (int2*)take((size_t)NTP * 8);
  float* y0     = (float*)take((size_t)NN * 64 * 4);
  float* z0     = (float*)take((size_t)NN * 64 * 4);
  float* zp     = (float*)take((size_t)NN * 64 * 4);
  float* zq     = (float*)take((size_t)NN * 64 * 4);
  (void)ws_size; (void)in_sizes; (void)n_in; (void)out_size;

  const int nblkN = (NN + 255) / 256;          // 196
  const int nblkE = (NE + 255) / 256;          // 3125
  const int nblkP = (NTP + 255) / 256;
  const int nbScan = (NN + 1023) / 1024;       // 49

  // --- fused weights (independent of graph) ---
  w13_kernel<<<64, 256, 0, stream>>>(W1, W3, W13);
  b13_kernel<<<1, 64, 0, stream>>>(b1, W3, b13);

  // --- graph norm + padded CSR build ---
  zero_deg_kernel<<<nblkN, 256, 0, stream>>>(deg);
  count_deg_kernel<<<nblkE, 256, 0, stream>>>(edst, deg);
  dinv_kernel<<<nblkN, 256, 0, stream>>>(deg, dinv);
  scan1_kernel<<<nbScan, 1024, 0, stream>>>(deg, incl, bsum);
  scan2_kernel<<<1, 64, 0, stream>>>(bsum, nbScan);
  scan3_kernel<<<nblkN, 256, 0, stream>>>(deg, incl, bsum, offs, cursor);
  zero_edges_kernel<<<nblkP, 256, 0, stream>>>(edges);
  fill_kernel<<<832, 256, 0, stream>>>(esrc, edst, dinv, cursor, edges);
  rowsum_kernel<<<nblkN, 256, 0, stream>>>(offs, edges, rsum);

  // --- y0 = x @ W13 + b13 ---
  gemm64_kernel<256><<<(NN + 63) / 64, 512, 0, stream>>>(x, W13, b13, y0, NN);

  const int pblk = (NN + 15) / 16;             // 3125

  // --- z0 = A_hat y0 ---
  prop64_kernel<0><<<pblk, 256, 0, stream>>>(y0, nullptr, z0, offs, edges, nullptr, nullptr);

  // --- APPNP in 64-dim: 10 x z = 0.9 A_hat z + 0.1 z0 ---
  const float* hc = z0;
  float* bufs[2] = {zp, zq};
  for (int it = 0; it < 10; ++it) {
    float* hn = bufs[it & 1];
    prop64_kernel<1><<<pblk, 256, 0, stream>>>(hc, z0, hn, offs, edges, nullptr, nullptr);
    hc = hn;
  }

  // --- out = A_hat z + rowsum * b3 ---
  prop64_kernel<2><<<pblk, 256, 0, stream>>>(hc, nullptr, outp, offs, edges, rsum, b3);
}

// Round 17
// 508.362 us; speedup vs baseline: 1.0300x; 1.0300x over previous
//
#include <hip/hip_runtime.h>

#define NN 50000            // nodes
#define NE 800000           // edges (without self loops)
#define NTP (NE + 8 * NN)   // padded-CSR capacity: sum pdeg <= NE+NN + 7*NN

// ---------------- graph preprocessing ----------------

__global__ void zero_deg_kernel(int* deg) {
  int v = blockIdx.x * 256 + threadIdx.x;
  if (v < NN) deg[v] = 0;
}

__global__ void count_deg_kernel(const int* __restrict__ edst, int* __restrict__ deg) {
  int i = blockIdx.x * 256 + threadIdx.x;
  if (i < NE) atomicAdd(&deg[edst[i]], 1);
}

__global__ void dinv_kernel(const int* __restrict__ deg, float* __restrict__ dinv) {
  int v = blockIdx.x * 256 + threadIdx.x;
  if (v < NN) dinv[v] = rsqrtf((float)(deg[v] + 1));   // +1 self loop
}

__device__ __forceinline__ int pdeg_of(int deg) {      // (deg+1) rounded up to x8
  return ((deg + 8) >> 3) << 3;
}

// inclusive scan of padded counts in chunks of 1024
__global__ __launch_bounds__(1024) void scan1_kernel(const int* __restrict__ deg,
                                                     int* __restrict__ incl,
                                                     int* __restrict__ bsum) {
  __shared__ int sd[1024];
  int gid = blockIdx.x * 1024 + threadIdx.x;
  int v = (gid < NN) ? pdeg_of(deg[gid]) : 0;
  sd[threadIdx.x] = v;
  __syncthreads();
  for (int off = 1; off < 1024; off <<= 1) {
    int t = (threadIdx.x >= off) ? sd[threadIdx.x - off] : 0;
    __syncthreads();
    sd[threadIdx.x] += t;
    __syncthreads();
  }
  if (gid < NN) incl[gid] = sd[threadIdx.x];
  if (threadIdx.x == 1023) bsum[blockIdx.x] = sd[1023];
}

__global__ void scan2_kernel(int* bsum, int nb) {
  if (threadIdx.x == 0 && blockIdx.x == 0) {
    int run = 0;
    for (int i = 0; i < nb; ++i) { int t = bsum[i]; bsum[i] = run; run += t; }
  }
}

__global__ void scan3_kernel(const int* __restrict__ deg, const int* __restrict__ incl,
                             const int* __restrict__ bsum, int* __restrict__ offs,
                             int* __restrict__ cursor) {
  int v = blockIdx.x * 256 + threadIdx.x;
  if (v >= NN) return;
  int pd = pdeg_of(deg[v]);
  int o = bsum[v >> 10] + incl[v] - pd;
  offs[v] = o;
  cursor[v] = o;
  if (v == NN - 1) offs[NN] = o + pd;
}

// zero padded edge array (int2 zeros -> weight 0 padding)
__global__ void zero_edges_kernel(int2* edges) {
  int i = blockIdx.x * 256 + threadIdx.x;
  if (i < NTP) edges[i] = make_int2(0, 0);
}

// scatter packed edge: .x = src, .y = float bits of weight
// grid-stride x4: 4 independent atomic->store chains in flight per thread.
#define FILL_STRIDE (832 * 256)
__global__ void fill_kernel(const int* __restrict__ esrc, const int* __restrict__ edst,
                            const float* __restrict__ dinv, int* __restrict__ cursor,
                            int2* __restrict__ edges) {
  int i = blockIdx.x * 256 + threadIdx.x;
  for (; i < NE + NN; i += FILL_STRIDE) {
    int s, d;
    if (i < NE) { s = esrc[i]; d = edst[i]; }
    else        { s = d = i - NE; }           // self loop
    int p = atomicAdd(&cursor[d], 1);
    int2 e;
    e.x = s;
    e.y = __float_as_int(dinv[s] * dinv[d]);
    edges[p] = e;
  }
}

// rowsum[v] = sum of weights (padding contributes 0)
__global__ void rowsum_kernel(const int* __restrict__ offs, const int2* __restrict__ edges,
                              float* __restrict__ rowsum) {
  int v = blockIdx.x * 256 + threadIdx.x;
  if (v >= NN) return;
  float s = 0.f;
  int e1 = offs[v + 1];
  for (int e = offs[v]; e < e1; ++e) s += __int_as_float(edges[e].y);
  rowsum[v] = s;
}

// ---------------- tiny fused-weight prep: W13 = W1 @ W3, b13 = b1 @ W3 ------

__global__ void w13_kernel(const float* __restrict__ W1, const float* __restrict__ W3,
                           float* __restrict__ W13) {
  int idx = blockIdx.x * 256 + threadIdx.x;   // 256*64 outputs
  if (idx >= 256 * 64) return;
  int r = idx >> 6, c = idx & 63;
  float acc = 0.f;
  for (int k = 0; k < 128; ++k) acc += W1[r * 128 + k] * W3[k * 64 + c];
  W13[idx] = acc;
}

__global__ void b13_kernel(const float* __restrict__ b1, const float* __restrict__ W3,
                           float* __restrict__ b13) {
  int c = threadIdx.x;   // 64 threads
  if (c >= 64) return;
  float acc = 0.f;
  for (int k = 0; k < 128; ++k) acc += b1[k] * W3[k * 64 + c];
  b13[c] = acc;
}

// ---------------- dense GEMM: out[M,64] = A[M,K] @ W[K,64] + bias -----------
// Best-measured config (R6: 44.2-44.6us): 256 threads, tile 32 rows x 64 cols,
// K-chunk 32, single-buffered, thread = 2 rows x 4 cols. LDS 12.4KB, grid
// 1563 (~6 blocks/CU). R11/R15/R16 lesson: every explicit pipeline variant
// (reg dbuf, 2-phase, global_load_lds DMA) loses more occupancy than it
// recovers in latency for this small tile -- TLP at minimal state wins.

template <int K>
__global__ __launch_bounds__(256) void gemm64_kernel(const float* __restrict__ A,
                                                     const float* __restrict__ W,
                                                     const float* __restrict__ bias,
                                                     float* __restrict__ out, int M) {
  __shared__ float xs[32][33];
  __shared__ float ws[32][64];

  int tid = threadIdx.x;
  int tc = tid >> 4;              // 0..15 col group (4 cols each)
  int tr = tid & 15;              // 0..15 row group (2 rows each)
  int row0 = blockIdx.x * 32;

  float acc[2][4] = {};

  for (int kc = 0; kc < K; kc += 32) {
    // stage xs: 32 rows x 32 k = 256 float4, one per thread
    {
      int r = tid >> 3, k4 = tid & 7;
      int row = row0 + r;
      float4 v = make_float4(0.f, 0.f, 0.f, 0.f);
      if (row < M) v = *reinterpret_cast<const float4*>(&A[(size_t)row * K + kc + k4 * 4]);
      xs[r][k4 * 4 + 0] = v.x;
      xs[r][k4 * 4 + 1] = v.y;
      xs[r][k4 * 4 + 2] = v.z;
      xs[r][k4 * 4 + 3] = v.w;
    }
    // stage ws: 32 k x 64 c = 512 float4, two per thread
    for (int i = tid; i < 512; i += 256) {
      int k = i >> 4, c4 = i & 15;
      *reinterpret_cast<float4*>(&ws[k][c4 * 4]) =
          *reinterpret_cast<const float4*>(&W[(size_t)(kc + k) * 64 + c4 * 4]);
    }
    __syncthreads();
#pragma unroll
    for (int k = 0; k < 32; ++k) {
      float x0 = xs[tr * 2 + 0][k];
      float x1 = xs[tr * 2 + 1][k];
      float4 wv = *reinterpret_cast<const float4*>(&ws[k][tc * 4]);
      acc[0][0] += x0 * wv.x; acc[0][1] += x0 * wv.y;
      acc[0][2] += x0 * wv.z; acc[0][3] += x0 * wv.w;
      acc[1][0] += x1 * wv.x; acc[1][1] += x1 * wv.y;
      acc[1][2] += x1 * wv.z; acc[1][3] += x1 * wv.w;
    }
    __syncthreads();
  }

  float4 bv = *reinterpret_cast<const float4*>(&bias[tc * 4]);
#pragma unroll
  for (int r = 0; r < 2; ++r) {
    int row = row0 + tr * 2 + r;
    if (row < M) {
      float4 o;
      o.x = acc[r][0] + bv.x;
      o.y = acc[r][1] + bv.y;
      o.z = acc[r][2] + bv.z;
      o.w = acc[r][3] + bv.w;
      *reinterpret_cast<float4*>(&out[(size_t)row * 64 + tc * 4]) = o;
    }
  }
}

// ---------------- propagation (F=64): out[d] = sum_e w_e * h[src_e] --------
// MODE 0: plain   MODE 1: APPNP (0.9*acc + 0.1*h0)   MODE 2: final (+rowsum*b3)
// 16 threads/node; padded 8-aligned int2 CSR segments -> no tails, int4
// metadata loads. At the random-gather transaction ceiling (R13/R14 evidence:
// XCD-slicing x2, degree-sort, src-ordering all null; 4- vs 8-deep unroll tie).

template <int MODE>
__global__ __launch_bounds__(256) void prop64_kernel(const float* __restrict__ hin,
                                                     const float* __restrict__ h0,
                                                     float* __restrict__ out,
                                                     const int* __restrict__ offs,
                                                     const int2* __restrict__ edges,
                                                     const float* __restrict__ rowsum,
                                                     const float* __restrict__ b3) {
  int node = blockIdx.x * 16 + (threadIdx.x >> 4);
  if (node >= NN) return;
  int f = (threadIdx.x & 15) * 4;
  const float* __restrict__ hb = hin + f;

  int e = offs[node];
  int e1 = offs[node + 1];
  float ax = 0.f, ay = 0.f, az = 0.f, aw = 0.f;

  for (; e < e1; e += 8) {
    int4 m01 = *reinterpret_cast<const int4*>(edges + e);
    int4 m23 = *reinterpret_cast<const int4*>(edges + e + 2);
    int4 m45 = *reinterpret_cast<const int4*>(edges + e + 4);
    int4 m67 = *reinterpret_cast<const int4*>(edges + e + 6);
    float4 v0 = *reinterpret_cast<const float4*>(hb + (size_t)m01.x * 64);
    float4 v1 = *reinterpret_cast<const float4*>(hb + (size_t)m01.z * 64);
    float4 v2 = *reinterpret_cast<const float4*>(hb + (size_t)m23.x * 64);
    float4 v3 = *reinterpret_cast<const float4*>(hb + (size_t)m23.z * 64);
    float4 v4 = *reinterpret_cast<const float4*>(hb + (size_t)m45.x * 64);
    float4 v5 = *reinterpret_cast<const float4*>(hb + (size_t)m45.z * 64);
    float4 v6 = *reinterpret_cast<const float4*>(hb + (size_t)m67.x * 64);
    float4 v7 = *reinterpret_cast<const float4*>(hb + (size_t)m67.z * 64);
    float w0 = __int_as_float(m01.y), w1 = __int_as_float(m01.w);
    float w2 = __int_as_float(m23.y), w3 = __int_as_float(m23.w);
    float w4 = __int_as_float(m45.y), w5 = __int_as_float(m45.w);
    float w6 = __int_as_float(m67.y), w7 = __int_as_float(m67.w);
    ax += w0 * v0.x + w1 * v1.x + w2 * v2.x + w3 * v3.x
        + w4 * v4.x + w5 * v5.x + w6 * v6.x + w7 * v7.x;
    ay += w0 * v0.y + w1 * v1.y + w2 * v2.y + w3 * v3.y
        + w4 * v4.y + w5 * v5.y + w6 * v6.y + w7 * v7.y;
    az += w0 * v0.z + w1 * v1.z + w2 * v2.z + w3 * v3.z
        + w4 * v4.z + w5 * v5.z + w6 * v6.z + w7 * v7.z;
    aw += w0 * v0.w + w1 * v1.w + w2 * v2.w + w3 * v3.w
        + w4 * v4.w + w5 * v5.w + w6 * v6.w + w7 * v7.w;
  }

  if (MODE == 1) {
    float4 z = *reinterpret_cast<const float4*>(&h0[(size_t)node * 64 + f]);
    ax = 0.9f * ax + 0.1f * z.x;
    ay = 0.9f * ay + 0.1f * z.y;
    az = 0.9f * az + 0.1f * z.z;
    aw = 0.9f * aw + 0.1f * z.w;
  }
  if (MODE == 2) {
    float rs = rowsum[node];
    float4 bz = *reinterpret_cast<const float4*>(&b3[f]);
    ax += rs * bz.x; ay += rs * bz.y; az += rs * bz.z; aw += rs * bz.w;
  }
  float4 o = make_float4(ax, ay, az, aw);
  *reinterpret_cast<float4*>(&out[(size_t)node * 64 + f]) = o;
}

// ---------------- launch ----------------

extern "C" void kernel_launch(void* const* d_in, const int* in_sizes, int n_in,
                              void* d_out, int out_size, void* d_ws, size_t ws_size,
                              hipStream_t stream) {
  const float* x    = (const float*)d_in[0];   // [50000,256]
  const int*   eidx = (const int*)d_in[1];     // [2,800000]
  const float* W1   = (const float*)d_in[2];   // [256,128]
  const float* b1   = (const float*)d_in[3];   // [128]
  const float* W3   = (const float*)d_in[4];   // [128,64]
  const float* b3   = (const float*)d_in[5];   // [64]
  float* outp = (float*)d_out;                 // [50000,64]

  const int* esrc = eidx;
  const int* edst = eidx + NE;

  // workspace layout (256B aligned)
  char* w = (char*)d_ws;
  size_t off = 0;
  auto take = [&](size_t bytes) {
    void* p = w + off;
    off = (off + bytes + 255) & ~(size_t)255;
    return p;
  };
  int*   deg    = (int*)take(NN * 4);
  float* dinv   = (float*)take(NN * 4);
  int*   incl   = (int*)take(NN * 4);
  int*   offs   = (int*)take((NN + 1) * 4);
  int*   cursor = (int*)take(NN * 4);
  int*   bsum   = (int*)take(64 * 4);
  float* rsum   = (float*)take(NN * 4);
  float* W13    = (float*)take(256 * 64 * 4);
  float* b13    = (float*)take(64 * 4);
  int2*  edges  = (int2*)take((size_t)NTP * 8);
  float* y0     = (float*)take((size_t)NN * 64 * 4);
  float* z0     = (float*)take((size_t)NN * 64 * 4);
  float* zp     = (float*)take((size_t)NN * 64 * 4);
  float* zq     = (float*)take((size_t)NN * 64 * 4);
  (void)ws_size; (void)in_sizes; (void)n_in; (void)out_size;

  const int nblkN = (NN + 255) / 256;          // 196
  const int nblkE = (NE + 255) / 256;          // 3125
  const int nblkP = (NTP + 255) / 256;
  const int nbScan = (NN + 1023) / 1024;       // 49

  // --- fused weights (independent of graph) ---
  w13_kernel<<<64, 256, 0, stream>>>(W1, W3, W13);
  b13_kernel<<<1, 64, 0, stream>>>(b1, W3, b13);

  // --- graph norm + padded CSR build ---
  zero_deg_kernel<<<nblkN, 256, 0, stream>>>(deg);
  count_deg_kernel<<<nblkE, 256, 0, stream>>>(edst, deg);
  dinv_kernel<<<nblkN, 256, 0, stream>>>(deg, dinv);
  scan1_kernel<<<nbScan, 1024, 0, stream>>>(deg, incl, bsum);
  scan2_kernel<<<1, 64, 0, stream>>>(bsum, nbScan);
  scan3_kernel<<<nblkN, 256, 0, stream>>>(deg, incl, bsum, offs, cursor);
  zero_edges_kernel<<<nblkP, 256, 0, stream>>>(edges);
  fill_kernel<<<832, 256, 0, stream>>>(esrc, edst, dinv, cursor, edges);
  rowsum_kernel<<<nblkN, 256, 0, stream>>>(offs, edges, rsum);

  // --- y0 = x @ W13 + b13 ---
  gemm64_kernel<256><<<(NN + 31) / 32, 256, 0, stream>>>(x, W13, b13, y0, NN);

  const int pblk = (NN + 15) / 16;             // 3125

  // --- z0 = A_hat y0 ---
  prop64_kernel<0><<<pblk, 256, 0, stream>>>(y0, nullptr, z0, offs, edges, nullptr, nullptr);

  // --- APPNP in 64-dim: 10 x z = 0.9 A_hat z + 0.1 z0 ---
  const float* hc = z0;
  float* bufs[2] = {zp, zq};
  for (int it = 0; it < 10; ++it) {
    float* hn = bufs[it & 1];
    prop64_kernel<1><<<pblk, 256, 0, stream>>>(hc, z0, hn, offs, edges, nullptr, nullptr);
    hc = hn;
  }

  // --- out = A_hat z + rowsum * b3 ---
  prop64_kernel<2><<<pblk, 256, 0, stream>>>(hc, nullptr, outp, offs, edges, rsum, b3);
}